// Round 2
// baseline (184.756 us; speedup 1.0000x reference)
//
#include <hip/hip_runtime.h>

// Resonate-and-fire neuron scan.
// x: [T, B, H] f32; omega, b_offset: [H] f32.
// out: concat(spike_post [T,B,H], mem_post [T,B,H]) f32.
// Sequential in T, parallel over B*H. Memory-bound (192 MiB total traffic).

#define DT 0.01f
#define VTHR 1.0f

constexpr int T = 128;
constexpr int B = 64;
constexpr int H = 2048;
constexpr int BH = B * H;  // 131072

__global__ __launch_bounds__(256) void rf_scan_kernel(
    const float* __restrict__ x,
    const float* __restrict__ omega,
    const float* __restrict__ b_offset,
    float* __restrict__ out)
{
    const int i = blockIdx.x * blockDim.x + threadIdx.x;  // flat (b,h)
    if (i >= BH) return;
    const int h = i & (H - 1);

    // Per-neuron coefficients (same for all b in the batch).
    const float wa  = fabsf(omega[h]);
    const float boa = fabsf(b_offset[h]);
    const float dw  = DT * wa;
    const float p_omega = (-1.0f + sqrtf(1.0f - dw * dw)) / DT;
    const float bcoef = p_omega - boa;

    float u = 0.0f, v = 0.0f, z = 0.0f;

    const float* xp = x + i;
    float* sp = out + i;                       // spike_post
    float* mp = out + (size_t)T * BH + i;      // mem_post

    #pragma unroll 4
    for (int t = 0; t < T; ++t) {
        const float xt = __builtin_nontemporal_load(xp + (size_t)t * BH);
        const float ur = u - z * VTHR;                         // hard reset
        const float nu = ur + (ur * bcoef - v * wa) * DT + xt * DT;
        const float nv = v + (ur * wa + v * bcoef) * DT;
        z = (nu - VTHR > 0.0f) ? 1.0f : 0.0f;
        u = nu;
        v = nv;
        __builtin_nontemporal_store(z, sp + (size_t)t * BH);
        __builtin_nontemporal_store(fmaxf(nu, 0.0f), mp + (size_t)t * BH);
    }
}

extern "C" void kernel_launch(void* const* d_in, const int* in_sizes, int n_in,
                              void* d_out, int out_size, void* d_ws, size_t ws_size,
                              hipStream_t stream) {
    const float* x        = (const float*)d_in[0];
    const float* omega    = (const float*)d_in[1];
    const float* b_offset = (const float*)d_in[2];
    float* out = (float*)d_out;

    const int threads = 256;
    const int blocks  = BH / threads;  // 512
    rf_scan_kernel<<<blocks, threads, 0, stream>>>(x, omega, b_offset, out);
}

// Round 3
// 184.232 us; speedup vs baseline: 1.0028x; 1.0028x over previous
//
#include <hip/hip_runtime.h>

// Resonate-and-fire neuron scan.
// x: [T, B, H] f32; omega, b_offset: [H] f32.
// out: concat(spike_post [T,B,H], mem_post [T,B,H]) f32.
// Sequential in T, parallel over B*H. Memory-bound (192 MiB total traffic).
//
// Round-3 change: preload ALL T=128 x-values into registers up front
// (state-independent addresses) so the memory pipe has ~32KB/wave in
// flight, instead of <=4 outstanding scalar loads gated by the serial
// scan chain. Scan then runs pure-VALU from registers.

#define DT 0.01f
#define VTHR 1.0f

constexpr int T = 128;
constexpr int B = 64;
constexpr int H = 2048;
constexpr int BH = B * H;  // 131072

__global__ __launch_bounds__(256) void rf_scan_kernel(
    const float* __restrict__ x,
    const float* __restrict__ omega,
    const float* __restrict__ b_offset,
    float* __restrict__ out)
{
    const int i = blockIdx.x * blockDim.x + threadIdx.x;  // flat (b,h)
    const int h = i & (H - 1);

    // Preload the entire time series for this neuron into registers.
    // Fully unrolled + compile-time indices -> stays in VGPRs (no scratch).
    float xr[T];
    const float* xp = x + i;
    #pragma unroll
    for (int t = 0; t < T; ++t) {
        xr[t] = __builtin_nontemporal_load(xp + (size_t)t * BH);
    }

    // Per-neuron coefficients (same for all b in the batch).
    const float wa  = fabsf(omega[h]);
    const float boa = fabsf(b_offset[h]);
    const float dw  = DT * wa;
    const float p_omega = (-1.0f + sqrtf(1.0f - dw * dw)) / DT;
    const float bcoef = p_omega - boa;

    float u = 0.0f, v = 0.0f, z = 0.0f;

    float* sp = out + i;                       // spike_post
    float* mp = out + (size_t)T * BH + i;      // mem_post

    #pragma unroll
    for (int t = 0; t < T; ++t) {
        const float xt = xr[t];
        const float ur = u - z * VTHR;                         // hard reset
        const float nu = ur + (ur * bcoef - v * wa) * DT + xt * DT;
        const float nv = v + (ur * wa + v * bcoef) * DT;
        z = (nu - VTHR > 0.0f) ? 1.0f : 0.0f;
        u = nu;
        v = nv;
        __builtin_nontemporal_store(z, sp + (size_t)t * BH);
        __builtin_nontemporal_store(fmaxf(nu, 0.0f), mp + (size_t)t * BH);
    }
}

extern "C" void kernel_launch(void* const* d_in, const int* in_sizes, int n_in,
                              void* d_out, int out_size, void* d_ws, size_t ws_size,
                              hipStream_t stream) {
    const float* x        = (const float*)d_in[0];
    const float* omega    = (const float*)d_in[1];
    const float* b_offset = (const float*)d_in[2];
    float* out = (float*)d_out;

    const int threads = 256;
    const int blocks  = BH / threads;  // 512
    rf_scan_kernel<<<blocks, threads, 0, stream>>>(x, omega, b_offset, out);
}